// Round 14
// baseline (508.152 us; speedup 1.0000x reference)
//
#include <hip/hip_runtime.h>
#include <stdint.h>

#define NB 64
#define DD 256
#define HH 512
#define NGROUP 2048

typedef __attribute__((ext_vector_type(8))) _Float16 half8;
typedef __attribute__((ext_vector_type(4))) _Float16 half4;
typedef __attribute__((ext_vector_type(4))) float f32x4;
typedef __attribute__((ext_vector_type(16))) float f32x16;

__device__ __forceinline__ half8 ld8(const _Float16* p) {
    return *reinterpret_cast<const half8*>(p);
}

// 16x16 fragment packing (R12, validated): [R][K] -> ((R>>4)*NKS + (K>>5))*512 ...
__device__ __forceinline__ int fragidx(int R, int K, int NKS) {
    return (((R >> 4) * NKS + (K >> 5)) * 64 + (((K >> 3) & 3) * 16 + (R & 15))) * 8 + (K & 7);
}
// 32x32 fragment packing (R13, validated)
__device__ __forceinline__ int fragidx32(int R, int K, int NK16) {
    return (((R >> 5) * NK16 + (K >> 4)) * 64 + (((K >> 3) & 1) * 32 + (R & 31))) * 8 + (K & 7);
}

// ---------------- merged prep kernel: G packed 32x32; UT/W2T packed 16x16 ----
__global__ void prep_all(const float* __restrict__ Wq1, const float* __restrict__ Wk1,
                         const float* __restrict__ Wv1, const float* __restrict__ Wq2,
                         const float* __restrict__ Wk2, const float* __restrict__ Wv2,
                         const float* __restrict__ W1, const float* __restrict__ W2,
                         _Float16* __restrict__ Gf1, _Float16* __restrict__ Gf2,
                         _Float16* __restrict__ UTf, _Float16* __restrict__ W2Tf,
                         float scale) {
    const int b = blockIdx.x, t = threadIdx.x;
    if (b < 512) {
        const float* A = (b < 256) ? Wq1 : Wq2;
        const float* Bm = (b < 256) ? Wk2 : Wk1;
        _Float16* G = (b < 256) ? Gf1 : Gf2;
        const int d = b & 255, e = t;
        const float4* qa = reinterpret_cast<const float4*>(A + d * HH);
        const float4* ka = reinterpret_cast<const float4*>(Bm + e * HH);
        float s = 0.f;
        #pragma unroll 8
        for (int j = 0; j < HH / 4; ++j) {
            float4 a = qa[j], bb = ka[j];
            s += a.x * bb.x + a.y * bb.y + a.z * bb.z + a.w * bb.w;
        }
        G[fragidx32(d, e, 16)] = (_Float16)(s * scale);
    } else if (b < 1536) {
        const int half = (b - 512) >> 9;
        const int o = (b - 512) & 511;
        const float* Wv = half ? Wv2 : Wv1;
        const float* W1p = W1 + half * HH * HH;
        const int d = t;
        const float4* va = reinterpret_cast<const float4*>(Wv + d * HH);
        float s = 0.f;
        #pragma unroll 4
        for (int j4 = 0; j4 < HH / 4; ++j4) {
            float4 a = va[j4];
            const int j = j4 * 4;
            s += a.x * W1p[(j + 0) * HH + o];
            s += a.y * W1p[(j + 1) * HH + o];
            s += a.z * W1p[(j + 2) * HH + o];
            s += a.w * W1p[(j + 3) * HH + o];
        }
        UTf[fragidx(o, half * 256 + d, 16)] = (_Float16)s;
    } else {
        __shared__ float tile[32][33];
        const int bi = b - 1536;
        const int bk = (bi & 15) * 32;
        const int bh = (bi >> 4) * 32;
        const int tx = t & 31, ty = t >> 5;
        #pragma unroll
        for (int i = 0; i < 32; i += 8)
            tile[ty + i][tx] = W2[(bh + ty + i) * HH + bk + tx];
        __syncthreads();
        #pragma unroll
        for (int i = 0; i < 32; i += 8) {
            const int R = bk + ty + i;
            const int K = bh + tx;
            W2Tf[fragidx(R, K, 16)] = (_Float16)tile[tx][ty + i];
        }
    }
}

// ---------------- main fused kernel ----------------
// 512 thr (8 waves), 80 KiB LDS -> 2 blocks/CU (two independent barrier domains).
// LDS:
//   X @ 0      [2][64][256] f16 ext-swz -> g1,g2 (PV transposes slices in place)
//   R @ 65536  16 KiB: A-chunk [2][64][64] | P [2][64][64] | h dbuf [2][64][64]
#define RBASE 65536

__device__ __forceinline__ int axX(int side, int row, int ec) {
    return side * 32768 + row * 512 +
           ((2 * ec) ^ ((row & 7) << 4) ^ (((row >> 3) & 1) << 7));
}
__device__ __forceinline__ int axR(int slot, int row, int ec) {   // 128B rows
    return RBASE + slot * 8192 + row * 128 + ((2 * ec) ^ ((row & 7) << 4));
}

__global__ __launch_bounds__(512, 4)
void fused_kernel(const float* __restrict__ x1g, const float* __restrict__ x2g,
                  const _Float16* __restrict__ Gf1, const _Float16* __restrict__ Gf2,
                  const _Float16* __restrict__ UTf, const _Float16* __restrict__ W2Tf,
                  const float* __restrict__ b1, const float* __restrict__ b2,
                  float* __restrict__ out) {
    __shared__ __align__(16) char lds[81920];

    const int tid = threadIdx.x;
    const int lane = tid & 63;
    const int w = tid >> 6;        // wave 0..7
    const int c = lane & 15;
    const int kg = lane >> 4;
    const int c5 = lane & 31;
    const int kg2 = lane >> 5;
    const size_t g = blockIdx.x;
    const f32x4 z = {0.f, 0.f, 0.f, 0.f};
    const f32x16 z16 = {0.f,0.f,0.f,0.f,0.f,0.f,0.f,0.f,0.f,0.f,0.f,0.f,0.f,0.f,0.f,0.f};
    #define ROWF(r) ((((r) & 3) + 8 * ((r) >> 2)) + 4 * kg2)

    // ==== P1: stage x -> f16 LDS ====
    {
        const float* xs0 = x1g + g * (NB * DD);
        const float* xs1 = x2g + g * (NB * DD);
        #pragma unroll
        for (int it = 0; it < 8; ++it) {
            const int row = 8 * w + it;
            float4 a = reinterpret_cast<const float4*>(xs0 + row * DD)[lane];
            float4 b = reinterpret_cast<const float4*>(xs1 + row * DD)[lane];
            half4 ha, hb;
            ha[0] = (_Float16)a.x; ha[1] = (_Float16)a.y; ha[2] = (_Float16)a.z; ha[3] = (_Float16)a.w;
            hb[0] = (_Float16)b.x; hb[1] = (_Float16)b.y; hb[2] = (_Float16)b.z; hb[3] = (_Float16)b.w;
            *reinterpret_cast<half4*>(lds + axX(0, row, 4 * lane)) = ha;
            *reinterpret_cast<half4*>(lds + axX(1, row, 4 * lane)) = hb;
        }
    }
    __syncthreads();

    // ==== Scores: 4 chunks of 64 d-cols; Sacc held in regs across chunks ====
    // wave roles (A-chunk, 32x32): side=w>>2, rb=(w>>1)&1, cb=w&1
    // wave roles (S-partial, 16x16): side=w>>2, wa=w&3
    f32x4 Sacc[4] = {z, z, z, z};
    const int sW = w >> 2;         // this wave's side for S/softmax/PV
    const int wa = w & 3;
    {
        const int rb = (w >> 1) & 1, cb = w & 1;
        const _Float16* Gsel = sW ? Gf2 : Gf1;   // side s computes A for its own S
        const int xo = 1 - sW;
        #pragma unroll 1
        for (int ci = 0; ci < 4; ++ci) {
            // A-chunk compute (32x32): rows 32rb.., cols 64ci+32cb..
            f32x16 acc = z16;
            #pragma unroll
            for (int ks = 0; ks < 16; ++ks) {
                half8 af = *reinterpret_cast<const half8*>(lds + axX(xo, 32 * rb + c5, 16 * ks + 8 * kg2));
                half8 bf = ld8(Gsel + (((2 * ci + cb) * 16 + ks) * 64 + lane) * 8);
                acc = __builtin_amdgcn_mfma_f32_32x32x16_f16(af, bf, acc, 0, 0, 0);
            }
            #pragma unroll
            for (int r = 0; r < 16; ++r)
                *reinterpret_cast<_Float16*>(lds + axR(sW, 32 * rb + ROWF(r), 32 * cb + c5)) = (_Float16)acc[r];
            __syncthreads();
            // S partial (16x16): rows 16wa of side sW, K = this chunk's 64 cols
            #pragma unroll
            for (int ks = 0; ks < 2; ++ks) {
                half8 af = *reinterpret_cast<const half8*>(lds + axX(sW, 16 * wa + c, 64 * ci + 32 * ks + 8 * kg));
                #pragma unroll
                for (int j = 0; j < 4; ++j) {
                    half8 bfr = *reinterpret_cast<const half8*>(lds + axR(sW, 16 * j + c, 32 * ks + 8 * kg));
                    Sacc[j] = __builtin_amdgcn_mfma_f32_16x16x32_f16(af, bfr, Sacc[j], 0, 0, 0);
                }
            }
            __syncthreads();
        }
    }

    // ==== Softmax (regs) -> P[side] in R ====
    {
        #pragma unroll
        for (int r = 0; r < 4; ++r) {
            float m0 = fmaxf(fmaxf(Sacc[0][r], Sacc[1][r]), fmaxf(Sacc[2][r], Sacc[3][r]));
            m0 = fmaxf(m0, __shfl_xor(m0, 1));
            m0 = fmaxf(m0, __shfl_xor(m0, 2));
            m0 = fmaxf(m0, __shfl_xor(m0, 4));
            m0 = fmaxf(m0, __shfl_xor(m0, 8));
            float e0 = __expf(Sacc[0][r] - m0);
            float e1 = __expf(Sacc[1][r] - m0);
            float e2 = __expf(Sacc[2][r] - m0);
            float e3 = __expf(Sacc[3][r] - m0);
            float s0 = e0 + e1 + e2 + e3;
            s0 += __shfl_xor(s0, 1);
            s0 += __shfl_xor(s0, 2);
            s0 += __shfl_xor(s0, 4);
            s0 += __shfl_xor(s0, 8);
            const float inv = 1.f / s0;
            const int row = 16 * wa + 4 * kg + r;
            *reinterpret_cast<_Float16*>(lds + axR(sW, row, 16 * 0 + c)) = (_Float16)(e0 * inv);
            *reinterpret_cast<_Float16*>(lds + axR(sW, row, 16 * 1 + c)) = (_Float16)(e1 * inv);
            *reinterpret_cast<_Float16*>(lds + axR(sW, row, 16 * 2 + c)) = (_Float16)(e2 * inv);
            *reinterpret_cast<_Float16*>(lds + axR(sW, row, 16 * 3 + c)) = (_Float16)(e3 * inv);
        }
    }
    __syncthreads();

    // ==== PV: 4 chunks; in-place 64x64 slice transpose inside X, then MFMA ====
    {
        half8 paf[4][2];
        #pragma unroll
        for (int i = 0; i < 4; ++i)
            #pragma unroll
            for (int ksp = 0; ksp < 2; ++ksp)
                paf[i][ksp] = *reinterpret_cast<const half8*>(lds + axR(sW, 16 * i + c, 32 * ksp + 8 * kg));

        const int tside = tid >> 8;          // threads 0-255: side0, 256-511: side1
        const int tloc = tid & 255;
        const int tm = tloc >> 2, tq = tloc & 3;
        #pragma unroll 1
        for (int ci = 0; ci < 4; ++ci) {
            // read slice elements (each element exactly once across the block)
            half8 v0 = *reinterpret_cast<const half8*>(lds + axX(tside, tm, 64 * ci + 16 * tq));
            half8 v1 = *reinterpret_cast<const half8*>(lds + axX(tside, tm, 64 * ci + 16 * tq + 8));
            __syncthreads();
            // write back transposed: XT(dl, m) at X-position (row=dl, ec=64ci+m)
            #pragma unroll
            for (int e = 0; e < 8; ++e) {
                *reinterpret_cast<_Float16*>(lds + axX(tside, 16 * tq + e,     64 * ci + tm)) = v0[e];
                *reinterpret_cast<_Float16*>(lds + axX(tside, 16 * tq + 8 + e, 64 * ci + tm)) = v1[e];
            }
            __syncthreads();
            // MFMA: wave (side sW, dl-tile wa): g rows 16i, col-block 64ci+16wa
            half8 bfr0 = *reinterpret_cast<const half8*>(lds + axX(sW, 16 * wa + c, 64 * ci + 8 * kg));
            half8 bfr1 = *reinterpret_cast<const half8*>(lds + axX(sW, 16 * wa + c, 64 * ci + 32 + 8 * kg));
            f32x4 ga[4];
            #pragma unroll
            for (int i = 0; i < 4; ++i) {
                f32x4 acc = z;
                acc = __builtin_amdgcn_mfma_f32_16x16x32_f16(paf[i][0], bfr0, acc, 0, 0, 0);
                acc = __builtin_amdgcn_mfma_f32_16x16x32_f16(paf[i][1], bfr1, acc, 0, 0, 0);
                ga[i] = acc;
            }
            __syncthreads();   // all XT reads done before g overwrites slice
            #pragma unroll
            for (int i = 0; i < 4; ++i)
                #pragma unroll
                for (int r = 0; r < 4; ++r)
                    *reinterpret_cast<_Float16*>(lds + axX(sW, 16 * i + 4 * kg + r, 64 * ci + 16 * wa + c)) = (_Float16)ga[i][r];
        }
    }
    __syncthreads();

    // ==== MLP: 8 chunks of 64 h-cols (dbuf); out^T acc in oacc[4][4] ====
    f32x4 oacc[4][4];
    #pragma unroll
    for (int i = 0; i < 4; ++i)
        #pragma unroll
        for (int j = 0; j < 4; ++j) oacc[i][j] = z;

    const int ct2 = w >> 1;        // h coltile (0..3) within chunk
    const int rh = w & 1;          // h rowtile-pair selector
    #pragma unroll 1
    for (int q = 0; q < 8; ++q) {
        const int buf = q & 1;
        // h chunk compute (16x16): wave: coltile ct2, rowtiles {2rh, 2rh+1}
        f32x4 hacc[2] = {z, z};
        #pragma unroll
        for (int ks = 0; ks < 16; ++ks) {
            const int side = ks >> 3, kk = ks & 7;
            half8 bf = ld8(UTf + (((4 * q + ct2) * 16 + ks) * 64 + lane) * 8);
            #pragma unroll
            for (int i2 = 0; i2 < 2; ++i2) {
                half8 af = *reinterpret_cast<const half8*>(lds + axX(side, 16 * (2 * rh + i2) + c, 32 * kk + 8 * kg));
                hacc[i2] = __builtin_amdgcn_mfma_f32_16x16x32_f16(af, bf, hacc[i2], 0, 0, 0);
            }
        }
        const float bb = b1[64 * q + 16 * ct2 + c];
        #pragma unroll
        for (int i2 = 0; i2 < 2; ++i2)
            #pragma unroll
            for (int r = 0; r < 4; ++r)
                *reinterpret_cast<_Float16*>(lds + axR(buf, 16 * (2 * rh + i2) + 4 * kg + r, 16 * ct2 + c)) =
                    (_Float16)fmaxf(hacc[i2][r] + bb, 0.f);
        __syncthreads();
        // out^T partial: wave owns ocols 64w..; K = this chunk (2 ksteps)
        #pragma unroll
        for (int ks = 0; ks < 2; ++ks) {
            half8 bfr2[4];
            #pragma unroll
            for (int nj = 0; nj < 4; ++nj)
                bfr2[nj] = *reinterpret_cast<const half8*>(lds + axR(buf, 16 * nj + c, 32 * ks + 8 * kg));
            #pragma unroll
            for (int i = 0; i < 4; ++i) {
                half8 af2 = ld8(W2Tf + (((4 * w + i) * 16 + 2 * q + ks) * 64 + lane) * 8);
                #pragma unroll
                for (int nj = 0; nj < 4; ++nj)
                    oacc[i][nj] = __builtin_amdgcn_mfma_f32_16x16x32_f16(af2, bfr2[nj], oacc[i][nj], 0, 0, 0);
            }
        }
        // no trailing sync: dbuf
    }

    // ==== Epilogue: coalesced float4 stores ====
    float* og = out + g * (size_t)(NB * HH);
    #pragma unroll
    for (int i = 0; i < 4; ++i) {
        const int ocol0 = 64 * w + 16 * i + 4 * kg;
        const float4 b2v = *reinterpret_cast<const float4*>(b2 + ocol0);
        #pragma unroll
        for (int nj = 0; nj < 4; ++nj) {
            float4 res;
            res.x = oacc[i][nj][0] + b2v.x;
            res.y = oacc[i][nj][1] + b2v.y;
            res.z = oacc[i][nj][2] + b2v.z;
            res.w = oacc[i][nj][3] + b2v.w;
            *reinterpret_cast<float4*>(og + (size_t)(16 * nj + c) * HH + ocol0) = res;
        }
    }
    #undef ROWF
}

// ---------------- launch ----------------

extern "C" void kernel_launch(void* const* d_in, const int* in_sizes, int n_in,
                              void* d_out, int out_size, void* d_ws, size_t ws_size,
                              hipStream_t stream) {
    (void)in_sizes; (void)n_in; (void)out_size; (void)ws_size;
    const float* x1  = (const float*)d_in[0];
    const float* x2  = (const float*)d_in[1];
    const float* Wq1 = (const float*)d_in[2];
    const float* Wk1 = (const float*)d_in[3];
    const float* Wv1 = (const float*)d_in[4];
    const float* Wq2 = (const float*)d_in[5];
    const float* Wk2 = (const float*)d_in[6];
    const float* Wv2 = (const float*)d_in[7];
    const float* W1  = (const float*)d_in[8];
    const float* b1  = (const float*)d_in[9];
    const float* W2  = (const float*)d_in[10];
    const float* b2  = (const float*)d_in[11];
    float* out = (float*)d_out;

    char* ws = (char*)d_ws;
    _Float16* Gf1  = (_Float16*)(ws + 0);        // 131072 (32x32-frag packed)
    _Float16* Gf2  = (_Float16*)(ws + 131072);   // 131072
    _Float16* UTf  = (_Float16*)(ws + 262144);   // 524288 (16x16-frag packed)
    _Float16* W2Tf = (_Float16*)(ws + 786432);   // 524288

    const float scale = 0.0625f;  // D^-0.5

    prep_all<<<1792, 256, 0, stream>>>(Wq1, Wk1, Wv1, Wq2, Wk2, Wv2, W1, W2,
                                       Gf1, Gf2, UTf, W2Tf, scale);
    fused_kernel<<<NGROUP, 512, 0, stream>>>(x1, x2, Gf1, Gf2, UTf, W2Tf, b1, b2, out);
}

// Round 15
// 437.875 us; speedup vs baseline: 1.1605x; 1.1605x over previous
//
#include <hip/hip_runtime.h>
#include <stdint.h>

#define NB 64
#define DD 256
#define HH 512
#define NGROUP 2048

typedef __attribute__((ext_vector_type(8))) _Float16 half8;
typedef __attribute__((ext_vector_type(4))) _Float16 half4;
typedef __attribute__((ext_vector_type(4))) float f32x4;

__device__ __forceinline__ half8 ld8(const _Float16* p) {
    return *reinterpret_cast<const half8*>(p);
}

// Fragment-packing index (R12, validated): matrix element [R][K]
// -> flat ((R>>4)*NKS + (K>>5))*512 + (((K>>3)&3)*16 + (R&15))*8 + (K&7)
__device__ __forceinline__ int fragidx(int R, int K, int NKS) {
    return (((R >> 4) * NKS + (K >> 5)) * 64 + (((K >> 3) & 3) * 16 + (R & 15))) * 8 + (K & 7);
}

// ---------------- merged prep kernel: compute + scatter-pack to fragment order ----
__global__ void prep_all(const float* __restrict__ Wq1, const float* __restrict__ Wk1,
                         const float* __restrict__ Wv1, const float* __restrict__ Wq2,
                         const float* __restrict__ Wk2, const float* __restrict__ Wv2,
                         const float* __restrict__ W1, const float* __restrict__ W2,
                         _Float16* __restrict__ Gf1, _Float16* __restrict__ Gf2,
                         _Float16* __restrict__ UTf, _Float16* __restrict__ W2Tf,
                         float scale) {
    const int b = blockIdx.x, t = threadIdx.x;
    if (b < 512) {
        const float* A = (b < 256) ? Wq1 : Wq2;
        const float* Bm = (b < 256) ? Wk2 : Wk1;
        _Float16* G = (b < 256) ? Gf1 : Gf2;
        const int d = b & 255, e = t;
        const float4* qa = reinterpret_cast<const float4*>(A + d * HH);
        const float4* ka = reinterpret_cast<const float4*>(Bm + e * HH);
        float s = 0.f;
        #pragma unroll 8
        for (int j = 0; j < HH / 4; ++j) {
            float4 a = qa[j], bb = ka[j];
            s += a.x * bb.x + a.y * bb.y + a.z * bb.z + a.w * bb.w;
        }
        G[fragidx(d, e, 8)] = (_Float16)(s * scale);   // R=d, K=e
    } else if (b < 1536) {
        const int half = (b - 512) >> 9;
        const int o = (b - 512) & 511;
        const float* Wv = half ? Wv2 : Wv1;
        const float* W1p = W1 + half * HH * HH;
        const int d = t;
        const float4* va = reinterpret_cast<const float4*>(Wv + d * HH);
        float s = 0.f;
        #pragma unroll 4
        for (int j4 = 0; j4 < HH / 4; ++j4) {
            float4 a = va[j4];
            const int j = j4 * 4;
            s += a.x * W1p[(j + 0) * HH + o];
            s += a.y * W1p[(j + 1) * HH + o];
            s += a.z * W1p[(j + 2) * HH + o];
            s += a.w * W1p[(j + 3) * HH + o];
        }
        UTf[fragidx(o, half * 256 + d, 16)] = (_Float16)s;   // R=o, K=side*256+d
    } else {
        __shared__ float tile[32][33];
        const int bi = b - 1536;
        const int bk = (bi & 15) * 32;
        const int bh = (bi >> 4) * 32;
        const int tx = t & 31, ty = t >> 5;
        #pragma unroll
        for (int i = 0; i < 32; i += 8)
            tile[ty + i][tx] = W2[(bh + ty + i) * HH + bk + tx];
        __syncthreads();
        #pragma unroll
        for (int i = 0; i < 32; i += 8) {
            const int R = bk + ty + i;   // W2T row (out col)
            const int K = bh + tx;       // contraction (h)
            W2Tf[fragidx(R, K, 16)] = (_Float16)tile[tx][ty + i];
        }
    }
}

// ---------------- main fused kernel (R12 winner, epilogue store-order fix) ------
// 1024 thr (16 waves), 144 KiB LDS, 1 blk/CU, 4 waves/SIMD.
//   X  @ 0       [2][64][256] f16 ext-swz -> becomes g1,g2
//   A  @ 65536   [2][64][256] f16         -> XT [2][256][64] -> h [64][512]
//   P  @ 131072  [2][64][64] f16
#define ABASE 65536
#define PBASE 131072

__device__ __forceinline__ int axX(int side, int row, int ec) {
    return side * 32768 + row * 512 +
           ((2 * ec) ^ ((row & 7) << 4) ^ (((row >> 3) & 1) << 7));
}
__device__ __forceinline__ int axA(int side, int row, int ec) {
    return ABASE + side * 32768 + row * 512 +
           ((2 * ec) ^ ((row & 7) << 4) ^ (((row >> 3) & 1) << 7));
}
__device__ __forceinline__ int axXT(int side, int row, int ec) {   // [256][64], 128B rows
    return ABASE + side * 32768 + row * 128 + ((2 * ec) ^ ((row & 7) << 4));
}
__device__ __forceinline__ int axH(int row, int ec) {              // [64][512], 1024B rows
    return ABASE + row * 1024 +
           ((2 * ec) ^ ((row & 7) << 4) ^ (((row >> 3) & 1) << 7));
}
__device__ __forceinline__ int axP(int side, int row, int ec) {    // [64][64], 128B rows
    return PBASE + side * 8192 + row * 128 + ((2 * ec) ^ ((row & 7) << 4));
}

__global__ __launch_bounds__(1024, 4)
void fused_kernel(const float* __restrict__ x1g, const float* __restrict__ x2g,
                  const _Float16* __restrict__ Gf1, const _Float16* __restrict__ Gf2,
                  const _Float16* __restrict__ UTf, const _Float16* __restrict__ W2Tf,
                  const float* __restrict__ b1, const float* __restrict__ b2,
                  float* __restrict__ out) {
    __shared__ __align__(16) char lds[147456];

    const int tid = threadIdx.x;
    const int lane = tid & 63;
    const int w = tid >> 6;        // wave 0..15
    const int c = lane & 15;
    const int kg = lane >> 4;
    const int s = w >> 3;          // side (waves 0-7: side0, 8-15: side1)
    const int ws = w & 7;          // 32-wide strip index within side
    const size_t g = blockIdx.x;
    const f32x4 z = {0.f, 0.f, 0.f, 0.f};

    // ==== P1: stage x -> f16 LDS ====
    {
        const float* xs0 = x1g + g * (NB * DD);
        const float* xs1 = x2g + g * (NB * DD);
        #pragma unroll
        for (int it = 0; it < 4; ++it) {
            const int row = 4 * w + it;
            float4 a = reinterpret_cast<const float4*>(xs0 + row * DD)[lane];
            float4 b = reinterpret_cast<const float4*>(xs1 + row * DD)[lane];
            half4 ha, hb;
            ha[0] = (_Float16)a.x; ha[1] = (_Float16)a.y; ha[2] = (_Float16)a.z; ha[3] = (_Float16)a.w;
            hb[0] = (_Float16)b.x; hb[1] = (_Float16)b.y; hb[2] = (_Float16)b.z; hb[3] = (_Float16)b.w;
            *reinterpret_cast<half4*>(lds + axX(0, row, 4 * lane)) = ha;
            *reinterpret_cast<half4*>(lds + axX(1, row, 4 * lane)) = hb;
        }
    }
    __syncthreads();

    // ==== P2: A-full. slotA[s] = X_{1-s} @ Gsel^T; wave owns 32 d-cols ====
    {
        const _Float16* Gsel = s ? Gf2 : Gf1;
        const int xo = 1 - s;
        f32x4 acc[4][2];
        #pragma unroll
        for (int i = 0; i < 4; ++i) { acc[i][0] = z; acc[i][1] = z; }
        #pragma unroll
        for (int ks = 0; ks < 8; ++ks) {
            half8 af[4];
            #pragma unroll
            for (int i = 0; i < 4; ++i)
                af[i] = *reinterpret_cast<const half8*>(lds + axX(xo, 16 * i + c, 32 * ks + 8 * kg));
            #pragma unroll
            for (int ct = 0; ct < 2; ++ct) {
                half8 bf = ld8(Gsel + (((2 * ws + ct) * 8 + ks) * 64 + lane) * 8);
                #pragma unroll
                for (int i = 0; i < 4; ++i)
                    acc[i][ct] = __builtin_amdgcn_mfma_f32_16x16x32_f16(af[i], bf, acc[i][ct], 0, 0, 0);
            }
        }
        #pragma unroll
        for (int i = 0; i < 4; ++i)
            #pragma unroll
            for (int ct = 0; ct < 2; ++ct)
                #pragma unroll
                for (int r = 0; r < 4; ++r)
                    *reinterpret_cast<_Float16*>(lds + axA(s, 16 * i + 4 * kg + r, 32 * ws + 16 * ct + c)) = (_Float16)acc[i][ct][r];
    }
    __syncthreads();

    // ==== P3: S (K=256) + softmax -> P[s]; 8 active waves (4 per side) ====
    if ((w & 4) == 0) {
        const int wa = w & 3;
        f32x4 Sacc[4] = {z, z, z, z};
        #pragma unroll
        for (int ks = 0; ks < 8; ++ks) {
            half8 af = *reinterpret_cast<const half8*>(lds + axX(s, 16 * wa + c, 32 * ks + 8 * kg));
            #pragma unroll
            for (int j = 0; j < 4; ++j) {
                half8 bfr = *reinterpret_cast<const half8*>(lds + axA(s, 16 * j + c, 32 * ks + 8 * kg));
                Sacc[j] = __builtin_amdgcn_mfma_f32_16x16x32_f16(af, bfr, Sacc[j], 0, 0, 0);
            }
        }
        #pragma unroll
        for (int r = 0; r < 4; ++r) {
            float m0 = fmaxf(fmaxf(Sacc[0][r], Sacc[1][r]), fmaxf(Sacc[2][r], Sacc[3][r]));
            m0 = fmaxf(m0, __shfl_xor(m0, 1));
            m0 = fmaxf(m0, __shfl_xor(m0, 2));
            m0 = fmaxf(m0, __shfl_xor(m0, 4));
            m0 = fmaxf(m0, __shfl_xor(m0, 8));
            float e0 = __expf(Sacc[0][r] - m0);
            float e1 = __expf(Sacc[1][r] - m0);
            float e2 = __expf(Sacc[2][r] - m0);
            float e3 = __expf(Sacc[3][r] - m0);
            float s0 = e0 + e1 + e2 + e3;
            s0 += __shfl_xor(s0, 1);
            s0 += __shfl_xor(s0, 2);
            s0 += __shfl_xor(s0, 4);
            s0 += __shfl_xor(s0, 8);
            const float inv = 1.f / s0;
            const int row = 16 * wa + 4 * kg + r;
            *reinterpret_cast<_Float16*>(lds + axP(s, row, 16 * 0 + c)) = (_Float16)(e0 * inv);
            *reinterpret_cast<_Float16*>(lds + axP(s, row, 16 * 1 + c)) = (_Float16)(e1 * inv);
            *reinterpret_cast<_Float16*>(lds + axP(s, row, 16 * 2 + c)) = (_Float16)(e2 * inv);
            *reinterpret_cast<_Float16*>(lds + axP(s, row, 16 * 3 + c)) = (_Float16)(e3 * inv);
        }
    }
    __syncthreads();

    // ==== P4: XT build over slotA (A dead); wave transposes 32 d-cols of X_s ====
    {
        #pragma unroll
        for (int jj = 0; jj < 4; ++jj) {
            half8 v = *reinterpret_cast<const half8*>(lds + axX(s, lane, 32 * ws + 8 * jj));
            #pragma unroll
            for (int e = 0; e < 8; ++e)
                *reinterpret_cast<_Float16*>(lds + axXT(s, 32 * ws + 8 * jj + e, lane)) = v[e];
        }
    }
    __syncthreads();

    // ==== P5: PV. g_s[:, 32ws..] = P_s @ X_s via XT; g overwrites X_s ====
    {
        half8 paf[4][2];
        #pragma unroll
        for (int i = 0; i < 4; ++i)
            #pragma unroll
            for (int ksp = 0; ksp < 2; ++ksp)
                paf[i][ksp] = *reinterpret_cast<const half8*>(lds + axP(s, 16 * i + c, 32 * ksp + 8 * kg));
        #pragma unroll
        for (int dt = 0; dt < 2; ++dt) {
            half8 bfr0 = *reinterpret_cast<const half8*>(lds + axXT(s, 32 * ws + 16 * dt + c, 8 * kg));
            half8 bfr1 = *reinterpret_cast<const half8*>(lds + axXT(s, 32 * ws + 16 * dt + c, 32 + 8 * kg));
            #pragma unroll
            for (int i = 0; i < 4; ++i) {
                f32x4 acc = z;
                acc = __builtin_amdgcn_mfma_f32_16x16x32_f16(paf[i][0], bfr0, acc, 0, 0, 0);
                acc = __builtin_amdgcn_mfma_f32_16x16x32_f16(paf[i][1], bfr1, acc, 0, 0, 0);
                #pragma unroll
                for (int r = 0; r < 4; ++r)
                    *reinterpret_cast<_Float16*>(lds + axX(s, 16 * i + 4 * kg + r, 32 * ws + 16 * dt + c)) = (_Float16)acc[r];
            }
        }
    }
    __syncthreads();

    // ==== P6: h-full = relu(g @ U + b1) -> h[64][512]; wave: 32 h-cols ====
    {
        f32x4 acc[4][2];
        #pragma unroll
        for (int i = 0; i < 4; ++i) { acc[i][0] = z; acc[i][1] = z; }
        #pragma unroll
        for (int ks = 0; ks < 16; ++ks) {
            const int side = ks >> 3, kk = ks & 7;
            half8 af[4];
            #pragma unroll
            for (int i = 0; i < 4; ++i)
                af[i] = *reinterpret_cast<const half8*>(lds + axX(side, 16 * i + c, 32 * kk + 8 * kg));
            #pragma unroll
            for (int ct = 0; ct < 2; ++ct) {
                half8 bf = ld8(UTf + (((2 * w + ct) * 16 + ks) * 64 + lane) * 8);
                #pragma unroll
                for (int i = 0; i < 4; ++i)
                    acc[i][ct] = __builtin_amdgcn_mfma_f32_16x16x32_f16(af[i], bf, acc[i][ct], 0, 0, 0);
            }
        }
        #pragma unroll
        for (int ct = 0; ct < 2; ++ct) {
            const float bb = b1[32 * w + 16 * ct + c];
            #pragma unroll
            for (int i = 0; i < 4; ++i)
                #pragma unroll
                for (int r = 0; r < 4; ++r)
                    *reinterpret_cast<_Float16*>(lds + axH(16 * i + 4 * kg + r, 32 * w + 16 * ct + c)) =
                        (_Float16)fmaxf(acc[i][ct][r] + bb, 0.f);
        }
    }
    __syncthreads();

    // ==== P7: out^T = W2T-rows x h (K=512) + b2; wave: 32 ocols ====
    {
        f32x4 oacc[2][4];
        #pragma unroll
        for (int i = 0; i < 2; ++i)
            #pragma unroll
            for (int nj = 0; nj < 4; ++nj) oacc[i][nj] = z;
        #pragma unroll
        for (int ks = 0; ks < 16; ++ks) {
            half8 bfr2[4];
            #pragma unroll
            for (int nj = 0; nj < 4; ++nj)
                bfr2[nj] = *reinterpret_cast<const half8*>(lds + axH(16 * nj + c, 32 * ks + 8 * kg));
            #pragma unroll
            for (int i = 0; i < 2; ++i) {
                half8 af2 = ld8(W2Tf + (((2 * w + i) * 16 + ks) * 64 + lane) * 8);
                #pragma unroll
                for (int nj = 0; nj < 4; ++nj)
                    oacc[i][nj] = __builtin_amdgcn_mfma_f32_16x16x32_f16(af2, bfr2[nj], oacc[i][nj], 0, 0, 0);
            }
        }
        // Epilogue: nj OUTER, i INNER -> per output row the two 64B half-lines
        // (cols 32w..32w+15 and 32w+16..31) issue back-to-back and coalesce.
        float* og = out + g * (size_t)(NB * HH);
        #pragma unroll
        for (int nj = 0; nj < 4; ++nj) {
            float* orow = og + (size_t)(16 * nj + c) * HH;
            #pragma unroll
            for (int i = 0; i < 2; ++i) {
                const int ocol0 = 32 * w + 16 * i + 4 * kg;
                const float4 b2v = *reinterpret_cast<const float4*>(b2 + ocol0);
                float4 res;
                res.x = oacc[i][nj][0] + b2v.x;
                res.y = oacc[i][nj][1] + b2v.y;
                res.z = oacc[i][nj][2] + b2v.z;
                res.w = oacc[i][nj][3] + b2v.w;
                *reinterpret_cast<float4*>(orow + ocol0) = res;
            }
        }
    }
}

// ---------------- launch ----------------

extern "C" void kernel_launch(void* const* d_in, const int* in_sizes, int n_in,
                              void* d_out, int out_size, void* d_ws, size_t ws_size,
                              hipStream_t stream) {
    (void)in_sizes; (void)n_in; (void)out_size; (void)ws_size;
    const float* x1  = (const float*)d_in[0];
    const float* x2  = (const float*)d_in[1];
    const float* Wq1 = (const float*)d_in[2];
    const float* Wk1 = (const float*)d_in[3];
    const float* Wv1 = (const float*)d_in[4];
    const float* Wq2 = (const float*)d_in[5];
    const float* Wk2 = (const float*)d_in[6];
    const float* Wv2 = (const float*)d_in[7];
    const float* W1  = (const float*)d_in[8];
    const float* b1  = (const float*)d_in[9];
    const float* W2  = (const float*)d_in[10];
    const float* b2  = (const float*)d_in[11];
    float* out = (float*)d_out;

    char* ws = (char*)d_ws;
    _Float16* Gf1  = (_Float16*)(ws + 0);        // 131072 (packed [16][8][64][8])
    _Float16* Gf2  = (_Float16*)(ws + 131072);   // 131072
    _Float16* UTf  = (_Float16*)(ws + 262144);   // 524288 (packed [32][16][64][8])
    _Float16* W2Tf = (_Float16*)(ws + 786432);   // 524288

    const float scale = 0.0625f;  // D^-0.5

    prep_all<<<1792, 256, 0, stream>>>(Wq1, Wk1, Wv1, Wq2, Wk2, Wv2, W1, W2,
                                       Gf1, Gf2, UTf, W2Tf, scale);
    fused_kernel<<<NGROUP, 1024, 0, stream>>>(x1, x2, Gf1, Gf2, UTf, W2Tf, b1, b2, out);
}